// Round 14
// baseline (117.104 us; speedup 1.0000x reference)
//
#include <hip/hip_runtime.h>
#include <hip/hip_bf16.h>
#include <stdint.h>

// ============================================================================
// ImageManifoldHead on MI355X (gfx950) — round 14
//
// Pipeline (4 launches):
//   prep_patchify: blocks 0-160 weight prep (WpT/WoT/Wcsg); 161+ patchify
//   gemm1:  Apat @ WpT^T + b_patch + pos -> x bf16   (v8)
//   manifold_v6: coords/K0 (split-K MFMA) + embed/LN (VALU)  [R13, proven]
//   gemm2:  x @ WoT^T + b_out -> out f32             (v8)
//
// gemm v8 — 2-phase prefetch at FULL occupancy (the untested cell):
//   BM=64, BN=128, BK=32, double-buffered LDS = 24 KB (same as the winning
//   v5 footprint -> 6 blocks/CU, grid 1568) + STAGE(t+1)-before-compute,
//   one vmcnt(0)+s_barrier per step. R6/R11 pipelines lost because they
//   cost blocks/CU; this one doesn't.
//   Swizzle: slot = ch ^ (r&3) ^ ((r>>2)&3), source-side + read-side.
// ============================================================================

typedef __bf16 bf16_t;
typedef bf16_t bf16x8 __attribute__((ext_vector_type(8)));
typedef bf16_t bf16x4 __attribute__((ext_vector_type(4)));
typedef float  f32x4  __attribute__((ext_vector_type(4)));

#define IMG     448
#define PSZ     16
#define NHP     28
#define NPATCH  784
#define PDIM    768
#define DMODEL  512
#define MROWS   25088

__device__ __forceinline__ void gload16(void* lds, const void* g) {
  __builtin_amdgcn_global_load_lds(
      (__attribute__((address_space(1))) void*)(uintptr_t)g,
      (__attribute__((address_space(3))) void*)lds,
      16, 0, 0);
}

// ---------------------------------------------------------------------------
// prep_patchify: blk 0-95 WpT tiles; 96-159 WoT tiles; 160 Wcsg; 161+ patchify
// ---------------------------------------------------------------------------
__global__ __launch_bounds__(256) void prep_patchify(
    const float* __restrict__ Wp, const float* __restrict__ Wo,
    const float* __restrict__ Wc, const float* __restrict__ Ws,
    const float* __restrict__ images,
    bf16_t* __restrict__ WpT, bf16_t* __restrict__ WoT,
    bf16_t* __restrict__ Wcsg, bf16_t* __restrict__ Apat)
{
  __shared__ __align__(16) char shmem[64 * 65 * 4];
  const int tid = threadIdx.x;
  const int blk = blockIdx.x;

  if (blk == 160) {
    for (int idx = tid; idx < 8192; idx += 256) {
      const int r = idx >> 9, n = idx & 511;
      float v = 0.f;
      if (r < 8)       v = Wc[n * 8 + r];
      else if (r < 12) v = Ws[n * 4 + (r - 8)];
      Wcsg[idx] = (bf16_t)v;
    }
    return;
  }

  if (blk < 160) {
    float (*t)[65] = (float(*)[65])shmem;
    const float* src;  bf16_t* dst;  int K, N, bx, by;
    if (blk < 96) { src = Wp; dst = WpT; K = PDIM;   N = DMODEL;
                    bx = (blk & 7) * 64;        by = (blk >> 3) * 64; }
    else          { src = Wo; dst = WoT; K = DMODEL; N = DMODEL;
                    bx = ((blk - 96) & 7) * 64; by = ((blk - 96) >> 3) * 64; }
    const int tx = tid & 63, ty = tid >> 6;
    #pragma unroll
    for (int r = ty; r < 64; r += 4)
      t[r][tx] = src[(size_t)(by + r) * N + (bx + tx)];
    __syncthreads();
    #pragma unroll
    for (int r = ty; r < 64; r += 4)
      dst[(size_t)(bx + r) * K + (by + tx)] = (bf16_t)t[tx][r];
    return;
  }

  // ---- patchify ----
  bf16_t (*t)[456] = (bf16_t(*)[456])shmem;
  const int bid = blk - 161;
  const int b = bid / 84, rem = bid % 84;
  const int c = rem / 28, ph = rem % 28;
  const float* src = images + ((size_t)(b * 3 + c) * IMG + ph * PSZ) * IMG;

  #pragma unroll
  for (int idx = tid; idx < 16 * 112; idx += 256) {
    const int i = idx / 112, x4 = idx % 112;
    const float4 v = *(const float4*)(src + (size_t)i * IMG + x4 * 4);
    bf16x4 w;
    w[0] = (bf16_t)v.x; w[1] = (bf16_t)v.y; w[2] = (bf16_t)v.z; w[3] = (bf16_t)v.w;
    *(bf16x4*)&t[i][x4 * 4] = w;
  }
  __syncthreads();

  const size_t mbase = (size_t)b * NPATCH + (size_t)ph * NHP;
  #pragma unroll
  for (int idx = tid; idx < 28 * 64; idx += 256) {
    const int pw = idx >> 6, e = idx & 63;
    const int i = e >> 2, j4 = e & 3;
    const bf16x4 w = *(const bf16x4*)&t[i][pw * 16 + j4 * 4];
    *(bf16x4*)&Apat[(mbase + pw) * PDIM + c * 256 + i * 16 + j4 * 4] = w;
  }
}

// ---------------------------------------------------------------------------
// gemm v8: C[M][512] = A[M][KDIM] @ BT[512][KDIM]^T
// BM=64, BN=128, BK=32, dbuf (24 KB LDS, 6 blocks/CU), 2-phase prefetch.
// grid = 1568 (1D), XCD-bijective swizzle; n-major (A L2-shared).
// ---------------------------------------------------------------------------
template<int KDIM, int EPI>
__global__ __launch_bounds__(256) void gemm_bf16(
    const bf16_t* __restrict__ A, const bf16_t* __restrict__ BT,
    const float* __restrict__ bias, const float* __restrict__ pos,
    void* __restrict__ outp)
{
  __shared__ bf16_t As[2][64 * 32];    // 2 x 4 KB
  __shared__ bf16_t Bs[2][128 * 32];   // 2 x 8 KB
  constexpr int NT = KDIM / 32;

  const int tid  = threadIdx.x;
  const int orig = blockIdx.x;
  const int wg   = (orig & 7) * 196 + (orig >> 3);   // bijective, 1568=8*196
  const int n0   = (wg & 3) * 128;
  const int m0   = (wg >> 2) * 64;

  const int wave = tid >> 6, lane = tid & 63;

  // staging: lane -> (row16 = lane>>2, ch = lane&3); fetch global chunk
  // ca4 = ch ^ swz(row) so LDS slot s of row r holds chunk s ^ swz(r).
  const int row16 = lane >> 2;
  const int ch    = lane & 3;
  const int swz   = (row16 & 3) ^ ((row16 >> 2) & 3);
  const int ca4   = ch ^ swz;

  const bf16_t* ag  = A  + (size_t)(m0 + wave * 16 + row16)      * KDIM + ca4 * 8;
  const bf16_t* bg0 = BT + (size_t)(n0 + wave * 32 + row16)      * KDIM + ca4 * 8;
  const bf16_t* bg1 = BT + (size_t)(n0 + wave * 32 + 16 + row16) * KDIM + ca4 * 8;

  const int wm = (wave >> 1) * 32;
  const int wn = (wave & 1) * 64;
  const int lr = lane & 15;
  const int lt = lane >> 4;

  auto STAGE = [&](int buf, int k0) {
    gload16(&As[buf][(wave * 16) * 32],      ag  + k0);
    gload16(&Bs[buf][(wave * 32) * 32],      bg0 + k0);
    gload16(&Bs[buf][(wave * 32 + 16) * 32], bg1 + k0);
  };

  f32x4 acc[2][4] = {};

  STAGE(0, 0);
  asm volatile("s_waitcnt vmcnt(0)" ::: "memory");
  __builtin_amdgcn_s_barrier();

  int buf = 0;
  for (int t = 0; t < NT; ++t) {
    // issue next tile's DMA first — flies during the compute phase below
    if (t + 1 < NT) STAGE(buf ^ 1, (t + 1) * 32);

    bf16x8 af[2], bfr[4];
    #pragma unroll
    for (int i = 0; i < 2; ++i) {
      const int r = wm + i * 16 + lr;
      const int slot = lt ^ (r & 3) ^ ((r >> 2) & 3);
      af[i] = *(const bf16x8*)&As[buf][r * 32 + slot * 8];
    }
    #pragma unroll
    for (int j = 0; j < 4; ++j) {
      const int r = wn + j * 16 + lr;
      const int slot = lt ^ (r & 3) ^ ((r >> 2) & 3);
      bfr[j] = *(const bf16x8*)&Bs[buf][r * 32 + slot * 8];
    }
    #pragma unroll
    for (int i = 0; i < 2; ++i)
      #pragma unroll
      for (int j = 0; j < 4; ++j)
        acc[i][j] = __builtin_amdgcn_mfma_f32_16x16x32_bf16(af[i], bfr[j], acc[i][j], 0, 0, 0);

    if (t + 1 < NT) {
      asm volatile("s_waitcnt vmcnt(0)" ::: "memory");  // next tile landed
      __builtin_amdgcn_s_barrier();                     // all waves certified
      buf ^= 1;
    }
  }

  // C/D layout: col = lane&15 (n), row = (lane>>4)*4 + reg (m)
  const int q4 = lt << 2;
  const int colb = n0 + wn;
  #pragma unroll
  for (int i = 0; i < 2; ++i) {
    #pragma unroll
    for (int r = 0; r < 4; ++r) {
      const int mm = m0 + wm + i * 16 + q4 + r;
      if (EPI == 0) {
        const int pp = mm % NPATCH;
        const float* pe = pos + (size_t)pp * DMODEL;
        bf16_t* orow = (bf16_t*)outp + (size_t)mm * DMODEL;
        #pragma unroll
        for (int j = 0; j < 4; ++j) {
          const int nn = colb + j * 16 + lr;
          orow[nn] = (bf16_t)(acc[i][j][r] + bias[nn] + pe[nn]);
        }
      } else {
        float* orow = (float*)outp + (size_t)mm * DMODEL;
        #pragma unroll
        for (int j = 0; j < 4; ++j) {
          const int nn = colb + j * 16 + lr;
          orow[nn] = acc[i][j][r] + bias[nn];
        }
      }
    }
  }
}

// ---------------------------------------------------------------------------
// manifold_v6 (R13, proven): coords/K0 split-K MFMA + embed/LN VALU.
// grid = MROWS/32 = 784; 4 waves/block.
// ---------------------------------------------------------------------------
__global__ __launch_bounds__(256) void manifold_v6(
    bf16_t* __restrict__ x, const bf16_t* __restrict__ Wcsg,
    const float* __restrict__ b_coord, const float* __restrict__ b_spinor,
    const float* __restrict__ We, const float* __restrict__ be,
    const float* __restrict__ gamma, const float* __restrict__ beta)
{
  __shared__ float pbuf[2][2][16][12];

  const int tid  = threadIdx.x;
  const int w    = tid >> 6;
  const int lane = tid & 63;
  const int rg   = w & 1;
  const int kh   = w >> 1;
  const int lr   = lane & 15;
  const int lk   = (lane >> 4) << 3;
  const int q4   = (lane >> 4) << 2;
  const size_t mbase = (size_t)blockIdx.x * 32;

  const bf16_t* xrow = x + (mbase + rg * 16 + lr) * DMODEL + kh * 256 + lk;
  const bf16_t* wrow = Wcsg + lr * DMODEL + kh * 256 + lk;
  f32x4 acc1 = {0.f, 0.f, 0.f, 0.f};
  #pragma unroll
  for (int ks = 0; ks < 8; ++ks) {
    const bf16x8 bf = *(const bf16x8*)(xrow + ks * 32);
    const bf16x8 wf = *(const bf16x8*)(wrow + ks * 32);
    acc1 = __builtin_amdgcn_mfma_f32_16x16x32_bf16(wf, bf, acc1, 0, 0, 0);
  }
  if (q4 < 12) {
    #pragma unroll
    for (int r = 0; r < 4; ++r) pbuf[kh][rg][lr][q4 + r] = acc1[r];
  }
  __syncthreads();

  const int n0 = lane * 8;
  f32x4 wlo[8], whi[8];
  #pragma unroll
  for (int dc = 0; dc < 8; ++dc) {
    wlo[dc] = *(const f32x4*)&We[dc * DMODEL + n0];
    whi[dc] = *(const f32x4*)&We[dc * DMODEL + n0 + 4];
  }
  const f32x4 beL = *(const f32x4*)&be[n0];
  const f32x4 beH = *(const f32x4*)&be[n0 + 4];
  const f32x4 gL  = *(const f32x4*)&gamma[n0];
  const f32x4 gH  = *(const f32x4*)&gamma[n0 + 4];
  const f32x4 btL = *(const f32x4*)&beta[n0];
  const f32x4 btH = *(const f32x4*)&beta[n0 + 4];
  float bc[8], bs[4];
  #pragma unroll
  for (int dc = 0; dc < 8; ++dc) bc[dc] = b_coord[dc];
  #pragma unroll
  for (int ds = 0; ds < 4; ++ds) bs[ds] = b_spinor[ds];

  #pragma unroll 2
  for (int rr = 0; rr < 8; ++rr) {
    const int rloc = w * 8 + rr;
    const int rg2  = rloc >> 4, r16 = rloc & 15;
    const float* p0 = &pbuf[0][rg2][r16][0];
    const float* p1 = &pbuf[1][rg2][r16][0];
    float c[8];
    #pragma unroll
    for (int dc = 0; dc < 8; ++dc) c[dc] = p0[dc] + p1[dc] + bc[dc];
    float k0 = 0.f;
    #pragma unroll
    for (int ds = 0; ds < 4; ++ds) {
      const float s = p0[8 + ds] + p1[8 + ds] + bs[ds];
      k0 += s * s;
    }

    const size_t row = mbase + rloc;
    const bf16x8 xv = *(const bf16x8*)(x + row * DMODEL + n0);

    float v[8];
    float s1 = 0.f, s2 = 0.f;
    #pragma unroll
    for (int e = 0; e < 4; ++e) {
      float xm = beL[e];
      #pragma unroll
      for (int dc = 0; dc < 8; ++dc) xm += c[dc] * wlo[dc][e];
      const float vv = xm * k0 + (float)xv[e];
      v[e] = vv; s1 += vv; s2 += vv * vv;
    }
    #pragma unroll
    for (int e = 0; e < 4; ++e) {
      float xm = beH[e];
      #pragma unroll
      for (int dc = 0; dc < 8; ++dc) xm += c[dc] * whi[dc][e];
      const float vv = xm * k0 + (float)xv[4 + e];
      v[4 + e] = vv; s1 += vv; s2 += vv * vv;
    }

    #pragma unroll
    for (int off = 1; off <= 32; off <<= 1) {
      s1 += __shfl_xor(s1, off, 64);
      s2 += __shfl_xor(s2, off, 64);
    }
    const float mu  = s1 * (1.f / 512.f);
    const float var = s2 * (1.f / 512.f) - mu * mu;
    const float rs  = rsqrtf(var + 1e-5f);

    bf16x8 o;
    #pragma unroll
    for (int e = 0; e < 4; ++e) {
      o[e]     = (bf16_t)((v[e]     - mu) * rs * gL[e] + btL[e]);
      o[4 + e] = (bf16_t)((v[4 + e] - mu) * rs * gH[e] + btH[e]);
    }
    *(bf16x8*)(x + row * DMODEL + n0) = o;
  }
}

// ---------------------------------------------------------------------------
extern "C" void kernel_launch(void* const* d_in, const int* in_sizes, int n_in,
                              void* d_out, int out_size, void* d_ws, size_t ws_size,
                              hipStream_t stream)
{
  const float* images    = (const float*)d_in[0];
  const float* W_patch   = (const float*)d_in[1];
  const float* b_patch   = (const float*)d_in[2];
  const float* pos_embed = (const float*)d_in[3];
  const float* W_coord   = (const float*)d_in[4];
  const float* b_coord   = (const float*)d_in[5];
  const float* W_spinor  = (const float*)d_in[6];
  const float* b_spinor  = (const float*)d_in[7];
  const float* W_embed   = (const float*)d_in[8];
  const float* b_embed   = (const float*)d_in[9];
  const float* ln_gamma  = (const float*)d_in[10];
  const float* ln_beta   = (const float*)d_in[11];
  const float* W_out     = (const float*)d_in[12];
  const float* b_out     = (const float*)d_in[13];
  float* out = (float*)d_out;

  const size_t SZ_APAT = (size_t)MROWS * PDIM * 2;     // 38,535,168
  const size_t SZ_X    = (size_t)MROWS * DMODEL * 2;   // 25,690,112
  const size_t SZ_WPT  = (size_t)DMODEL * PDIM * 2;    //    786,432
  const size_t SZ_WOT  = (size_t)DMODEL * DMODEL * 2;  //    524,288

  char* ws = (char*)d_ws;
  char* p  = ws;
  bf16_t* Apat = (bf16_t*)p;   p += SZ_APAT;
  bf16_t* x    = (bf16_t*)p;   p += SZ_X;
  bf16_t* WpT  = (bf16_t*)p;   p += SZ_WPT;
  bf16_t* WoT  = (bf16_t*)p;   p += SZ_WOT;
  bf16_t* Wcsg = (bf16_t*)p;

  hipLaunchKernelGGL(prep_patchify, dim3(161 + 32 * 3 * 28), dim3(256), 0, stream,
                     W_patch, W_out, W_coord, W_spinor, images,
                     WpT, WoT, Wcsg, Apat);

  hipLaunchKernelGGL((gemm_bf16<PDIM, 0>), dim3(1568), dim3(256), 0, stream,
                     Apat, WpT, b_patch, pos_embed, (void*)x);

  hipLaunchKernelGGL(manifold_v6, dim3(MROWS / 32), dim3(256), 0, stream,
                     x, Wcsg, b_coord, b_spinor, W_embed, b_embed, ln_gamma, ln_beta);

  hipLaunchKernelGGL((gemm_bf16<DMODEL, 1>), dim3(1568), dim3(256), 0, stream,
                     x, WoT, b_out, (const float*)nullptr, (void*)out);
}

// Round 15
// 102.320 us; speedup vs baseline: 1.1445x; 1.1445x over previous
//
#include <hip/hip_runtime.h>
#include <hip/hip_bf16.h>
#include <stdint.h>

// ============================================================================
// ImageManifoldHead on MI355X (gfx950) — round 15
//
// Pipeline (4 launches) — R13 champion + merged prep launch + occupancy cap:
//   prep_patchify: blk 0-159 weight transposes; 160 Wcsg; 161+ patchify
//   gemm1:  Apat @ WpT^T + b_patch + pos -> x bf16   (v5, BK=64, launch_bounds(256,6))
//   manifold_v6: coords/K0 (split-K MFMA) + embed/LN (VALU)
//   gemm2:  x @ WoT^T + b_out -> out f32             (v5)
//
// R14 lesson: BK=32 2-phase + 4-slot swizzle = 3.6M bank conflicts + 2x
// barriers -> regression. Schedule space exhausted; revert to champion.
// Only new knob: __launch_bounds__(256,6) so VGPR cap (85) matches the
// LDS-implied 6 blocks/CU.
// ============================================================================

typedef __bf16 bf16_t;
typedef bf16_t bf16x8 __attribute__((ext_vector_type(8)));
typedef bf16_t bf16x4 __attribute__((ext_vector_type(4)));
typedef float  f32x4  __attribute__((ext_vector_type(4)));

#define IMG     448
#define PSZ     16
#define NHP     28
#define NPATCH  784
#define PDIM    768
#define DMODEL  512
#define MROWS   25088

__device__ __forceinline__ void gload16(void* lds, const void* g) {
  __builtin_amdgcn_global_load_lds(
      (__attribute__((address_space(1))) void*)(uintptr_t)g,
      (__attribute__((address_space(3))) void*)lds,
      16, 0, 0);
}

// ---------------------------------------------------------------------------
// prep_patchify: blk 0-95 WpT tiles; 96-159 WoT tiles; 160 Wcsg; 161+ patchify
// ---------------------------------------------------------------------------
__global__ __launch_bounds__(256) void prep_patchify(
    const float* __restrict__ Wp, const float* __restrict__ Wo,
    const float* __restrict__ Wc, const float* __restrict__ Ws,
    const float* __restrict__ images,
    bf16_t* __restrict__ WpT, bf16_t* __restrict__ WoT,
    bf16_t* __restrict__ Wcsg, bf16_t* __restrict__ Apat)
{
  __shared__ __align__(16) char shmem[64 * 65 * 4];
  const int tid = threadIdx.x;
  const int blk = blockIdx.x;

  if (blk == 160) {
    for (int idx = tid; idx < 8192; idx += 256) {
      const int r = idx >> 9, n = idx & 511;
      float v = 0.f;
      if (r < 8)       v = Wc[n * 8 + r];
      else if (r < 12) v = Ws[n * 4 + (r - 8)];
      Wcsg[idx] = (bf16_t)v;
    }
    return;
  }

  if (blk < 160) {
    float (*t)[65] = (float(*)[65])shmem;
    const float* src;  bf16_t* dst;  int K, N, bx, by;
    if (blk < 96) { src = Wp; dst = WpT; K = PDIM;   N = DMODEL;
                    bx = (blk & 7) * 64;        by = (blk >> 3) * 64; }
    else          { src = Wo; dst = WoT; K = DMODEL; N = DMODEL;
                    bx = ((blk - 96) & 7) * 64; by = ((blk - 96) >> 3) * 64; }
    const int tx = tid & 63, ty = tid >> 6;
    #pragma unroll
    for (int r = ty; r < 64; r += 4)
      t[r][tx] = src[(size_t)(by + r) * N + (bx + tx)];
    __syncthreads();
    #pragma unroll
    for (int r = ty; r < 64; r += 4)
      dst[(size_t)(bx + r) * K + (by + tx)] = (bf16_t)t[tx][r];
    return;
  }

  // ---- patchify ----
  bf16_t (*t)[456] = (bf16_t(*)[456])shmem;
  const int bid = blk - 161;
  const int b = bid / 84, rem = bid % 84;
  const int c = rem / 28, ph = rem % 28;
  const float* src = images + ((size_t)(b * 3 + c) * IMG + ph * PSZ) * IMG;

  #pragma unroll
  for (int idx = tid; idx < 16 * 112; idx += 256) {
    const int i = idx / 112, x4 = idx % 112;
    const float4 v = *(const float4*)(src + (size_t)i * IMG + x4 * 4);
    bf16x4 w;
    w[0] = (bf16_t)v.x; w[1] = (bf16_t)v.y; w[2] = (bf16_t)v.z; w[3] = (bf16_t)v.w;
    *(bf16x4*)&t[i][x4 * 4] = w;
  }
  __syncthreads();

  const size_t mbase = (size_t)b * NPATCH + (size_t)ph * NHP;
  #pragma unroll
  for (int idx = tid; idx < 28 * 64; idx += 256) {
    const int pw = idx >> 6, e = idx & 63;
    const int i = e >> 2, j4 = e & 3;
    const bf16x4 w = *(const bf16x4*)&t[i][pw * 16 + j4 * 4];
    *(bf16x4*)&Apat[(mbase + pw) * PDIM + c * 256 + i * 16 + j4 * 4] = w;
  }
}

// ---------------------------------------------------------------------------
// gemm v5 (R13 champion): C[M][512] = A[M][KDIM] @ BT[512][KDIM]^T
// BM=64, BN=128, BK=64, 4 waves, 24 KB LDS, grid 1568, XCD swizzle,
// chunk-XOR swizzle c ^ (row&7) both sides (bank conflicts = 0, verified).
// __launch_bounds__(256,6): VGPR cap so 6 blocks/CU (LDS limit) is reachable.
// ---------------------------------------------------------------------------
template<int KDIM, int EPI>
__global__ __launch_bounds__(256, 6) void gemm_bf16(
    const bf16_t* __restrict__ A, const bf16_t* __restrict__ BT,
    const float* __restrict__ bias, const float* __restrict__ pos,
    void* __restrict__ outp)
{
  __shared__ bf16_t As[64 * 64];    //  8 KB
  __shared__ bf16_t Bs[128 * 64];   // 16 KB
  constexpr int NT = KDIM / 64;

  const int tid  = threadIdx.x;
  const int orig = blockIdx.x;
  const int wg   = (orig & 7) * 196 + (orig >> 3);   // bijective, 1568=8*196
  const int n0   = (wg & 3) * 128;
  const int m0   = (wg >> 2) * 64;

  const int wave = tid >> 6, lane = tid & 63;

  const int ra = lane >> 3;
  const int ca = (lane & 7) ^ ra;
  const bf16_t* ag = A  + (size_t)(m0 + wave * 8 + ra) * KDIM + ca * 8;
  const bf16_t* bg = BT + (size_t)(n0 + wave * 8 + ra) * KDIM + ca * 8;
  bf16_t* al0 = As + (wave * 8) * 64;
  bf16_t* al1 = As + (wave * 8 + 32) * 64;
  bf16_t* bl0 = Bs + (wave * 8) * 64;
  bf16_t* bl1 = Bs + (wave * 8 + 32) * 64;
  bf16_t* bl2 = Bs + (wave * 8 + 64) * 64;
  bf16_t* bl3 = Bs + (wave * 8 + 96) * 64;

  const int wm = (wave >> 1) * 32;
  const int wn = (wave & 1) * 64;
  const int lr = lane & 15;
  const int lt = lane >> 4;

  f32x4 acc[2][4] = {};

  for (int t = 0; t < NT; ++t) {
    const int k0 = t * 64;
    __syncthreads();
    gload16(al0, ag + k0);
    gload16(al1, ag + 32 * KDIM + k0);
    gload16(bl0, bg + k0);
    gload16(bl1, bg + 32 * KDIM + k0);
    gload16(bl2, bg + 64 * KDIM + k0);
    gload16(bl3, bg + 96 * KDIM + k0);
    __syncthreads();

    #pragma unroll
    for (int ks = 0; ks < 2; ++ks) {
      const int c = ks * 4 + lt;
      bf16x8 af[2], bfr[4];
      #pragma unroll
      for (int i = 0; i < 2; ++i) {
        const int row = wm + i * 16 + lr;
        af[i] = *(const bf16x8*)&As[row * 64 + ((c ^ (row & 7)) * 8)];
      }
      #pragma unroll
      for (int j = 0; j < 4; ++j) {
        const int row = wn + j * 16 + lr;
        bfr[j] = *(const bf16x8*)&Bs[row * 64 + ((c ^ (row & 7)) * 8)];
      }
      #pragma unroll
      for (int i = 0; i < 2; ++i)
        #pragma unroll
        for (int j = 0; j < 4; ++j)
          acc[i][j] = __builtin_amdgcn_mfma_f32_16x16x32_bf16(af[i], bfr[j], acc[i][j], 0, 0, 0);
    }
  }

  const int q4 = lt << 2;
  const int colb = n0 + wn;
  #pragma unroll
  for (int i = 0; i < 2; ++i) {
    #pragma unroll
    for (int r = 0; r < 4; ++r) {
      const int mm = m0 + wm + i * 16 + q4 + r;
      if (EPI == 0) {
        const int pp = mm % NPATCH;
        const float* pe = pos + (size_t)pp * DMODEL;
        bf16_t* orow = (bf16_t*)outp + (size_t)mm * DMODEL;
        #pragma unroll
        for (int j = 0; j < 4; ++j) {
          const int nn = colb + j * 16 + lr;
          orow[nn] = (bf16_t)(acc[i][j][r] + bias[nn] + pe[nn]);
        }
      } else {
        float* orow = (float*)outp + (size_t)mm * DMODEL;
        #pragma unroll
        for (int j = 0; j < 4; ++j) {
          const int nn = colb + j * 16 + lr;
          orow[nn] = acc[i][j][r] + bias[nn];
        }
      }
    }
  }
}

// ---------------------------------------------------------------------------
// manifold_v6 (R13, proven): coords/K0 split-K MFMA + embed/LN VALU.
// grid = MROWS/32 = 784; 4 waves/block.
// ---------------------------------------------------------------------------
__global__ __launch_bounds__(256) void manifold_v6(
    bf16_t* __restrict__ x, const bf16_t* __restrict__ Wcsg,
    const float* __restrict__ b_coord, const float* __restrict__ b_spinor,
    const float* __restrict__ We, const float* __restrict__ be,
    const float* __restrict__ gamma, const float* __restrict__ beta)
{
  __shared__ float pbuf[2][2][16][12];

  const int tid  = threadIdx.x;
  const int w    = tid >> 6;
  const int lane = tid & 63;
  const int rg   = w & 1;
  const int kh   = w >> 1;
  const int lr   = lane & 15;
  const int lk   = (lane >> 4) << 3;
  const int q4   = (lane >> 4) << 2;
  const size_t mbase = (size_t)blockIdx.x * 32;

  const bf16_t* xrow = x + (mbase + rg * 16 + lr) * DMODEL + kh * 256 + lk;
  const bf16_t* wrow = Wcsg + lr * DMODEL + kh * 256 + lk;
  f32x4 acc1 = {0.f, 0.f, 0.f, 0.f};
  #pragma unroll
  for (int ks = 0; ks < 8; ++ks) {
    const bf16x8 bf = *(const bf16x8*)(xrow + ks * 32);
    const bf16x8 wf = *(const bf16x8*)(wrow + ks * 32);
    acc1 = __builtin_amdgcn_mfma_f32_16x16x32_bf16(wf, bf, acc1, 0, 0, 0);
  }
  if (q4 < 12) {
    #pragma unroll
    for (int r = 0; r < 4; ++r) pbuf[kh][rg][lr][q4 + r] = acc1[r];
  }
  __syncthreads();

  const int n0 = lane * 8;
  f32x4 wlo[8], whi[8];
  #pragma unroll
  for (int dc = 0; dc < 8; ++dc) {
    wlo[dc] = *(const f32x4*)&We[dc * DMODEL + n0];
    whi[dc] = *(const f32x4*)&We[dc * DMODEL + n0 + 4];
  }
  const f32x4 beL = *(const f32x4*)&be[n0];
  const f32x4 beH = *(const f32x4*)&be[n0 + 4];
  const f32x4 gL  = *(const f32x4*)&gamma[n0];
  const f32x4 gH  = *(const f32x4*)&gamma[n0 + 4];
  const f32x4 btL = *(const f32x4*)&beta[n0];
  const f32x4 btH = *(const f32x4*)&beta[n0 + 4];
  float bc[8], bs[4];
  #pragma unroll
  for (int dc = 0; dc < 8; ++dc) bc[dc] = b_coord[dc];
  #pragma unroll
  for (int ds = 0; ds < 4; ++ds) bs[ds] = b_spinor[ds];

  #pragma unroll 2
  for (int rr = 0; rr < 8; ++rr) {
    const int rloc = w * 8 + rr;
    const int rg2  = rloc >> 4, r16 = rloc & 15;
    const float* p0 = &pbuf[0][rg2][r16][0];
    const float* p1 = &pbuf[1][rg2][r16][0];
    float c[8];
    #pragma unroll
    for (int dc = 0; dc < 8; ++dc) c[dc] = p0[dc] + p1[dc] + bc[dc];
    float k0 = 0.f;
    #pragma unroll
    for (int ds = 0; ds < 4; ++ds) {
      const float s = p0[8 + ds] + p1[8 + ds] + bs[ds];
      k0 += s * s;
    }

    const size_t row = mbase + rloc;
    const bf16x8 xv = *(const bf16x8*)(x + row * DMODEL + n0);

    float v[8];
    float s1 = 0.f, s2 = 0.f;
    #pragma unroll
    for (int e = 0; e < 4; ++e) {
      float xm = beL[e];
      #pragma unroll
      for (int dc = 0; dc < 8; ++dc) xm += c[dc] * wlo[dc][e];
      const float vv = xm * k0 + (float)xv[e];
      v[e] = vv; s1 += vv; s2 += vv * vv;
    }
    #pragma unroll
    for (int e = 0; e < 4; ++e) {
      float xm = beH[e];
      #pragma unroll
      for (int dc = 0; dc < 8; ++dc) xm += c[dc] * whi[dc][e];
      const float vv = xm * k0 + (float)xv[4 + e];
      v[4 + e] = vv; s1 += vv; s2 += vv * vv;
    }

    #pragma unroll
    for (int off = 1; off <= 32; off <<= 1) {
      s1 += __shfl_xor(s1, off, 64);
      s2 += __shfl_xor(s2, off, 64);
    }
    const float mu  = s1 * (1.f / 512.f);
    const float var = s2 * (1.f / 512.f) - mu * mu;
    const float rs  = rsqrtf(var + 1e-5f);

    bf16x8 o;
    #pragma unroll
    for (int e = 0; e < 4; ++e) {
      o[e]     = (bf16_t)((v[e]     - mu) * rs * gL[e] + btL[e]);
      o[4 + e] = (bf16_t)((v[4 + e] - mu) * rs * gH[e] + btH[e]);
    }
    *(bf16x8*)(x + row * DMODEL + n0) = o;
  }
}

// ---------------------------------------------------------------------------
extern "C" void kernel_launch(void* const* d_in, const int* in_sizes, int n_in,
                              void* d_out, int out_size, void* d_ws, size_t ws_size,
                              hipStream_t stream)
{
  const float* images    = (const float*)d_in[0];
  const float* W_patch   = (const float*)d_in[1];
  const float* b_patch   = (const float*)d_in[2];
  const float* pos_embed = (const float*)d_in[3];
  const float* W_coord   = (const float*)d_in[4];
  const float* b_coord   = (const float*)d_in[5];
  const float* W_spinor  = (const float*)d_in[6];
  const float* b_spinor  = (const float*)d_in[7];
  const float* W_embed   = (const float*)d_in[8];
  const float* b_embed   = (const float*)d_in[9];
  const float* ln_gamma  = (const float*)d_in[10];
  const float* ln_beta   = (const float*)d_in[11];
  const float* W_out     = (const float*)d_in[12];
  const float* b_out     = (const float*)d_in[13];
  float* out = (float*)d_out;

  const size_t SZ_APAT = (size_t)MROWS * PDIM * 2;     // 38,535,168
  const size_t SZ_X    = (size_t)MROWS * DMODEL * 2;   // 25,690,112
  const size_t SZ_WPT  = (size_t)DMODEL * PDIM * 2;    //    786,432
  const size_t SZ_WOT  = (size_t)DMODEL * DMODEL * 2;  //    524,288

  char* ws = (char*)d_ws;
  char* p  = ws;
  bf16_t* Apat = (bf16_t*)p;   p += SZ_APAT;
  bf16_t* x    = (bf16_t*)p;   p += SZ_X;
  bf16_t* WpT  = (bf16_t*)p;   p += SZ_WPT;
  bf16_t* WoT  = (bf16_t*)p;   p += SZ_WOT;
  bf16_t* Wcsg = (bf16_t*)p;

  hipLaunchKernelGGL(prep_patchify, dim3(161 + 32 * 3 * 28), dim3(256), 0, stream,
                     W_patch, W_out, W_coord, W_spinor, images,
                     WpT, WoT, Wcsg, Apat);

  hipLaunchKernelGGL((gemm_bf16<PDIM, 0>), dim3(1568), dim3(256), 0, stream,
                     Apat, WpT, b_patch, pos_embed, (void*)x);

  hipLaunchKernelGGL(manifold_v6, dim3(MROWS / 32), dim3(256), 0, stream,
                     x, Wcsg, b_coord, b_spinor, W_embed, b_embed, ln_gamma, ln_beta);

  hipLaunchKernelGGL((gemm_bf16<DMODEL, 1>), dim3(1568), dim3(256), 0, stream,
                     x, WoT, b_out, (const float*)nullptr, (void*)out);
}

// Round 16
// 101.026 us; speedup vs baseline: 1.1591x; 1.0128x over previous
//
#include <hip/hip_runtime.h>
#include <hip/hip_bf16.h>
#include <stdint.h>

// ============================================================================
// ImageManifoldHead on MI355X (gfx950) — round 16
//
// Pipeline (4 launches):
//   prep_patchify: blk 0-159 weight transposes; 160 Wcsg; 161+ patchify
//   gemm1:  Apat @ WpT^T + b_patch + pos -> x bf16   (v5 champion, lb(256,6))
//   manifold_v7: split-K x4, 16 rows/block, grid 1568 (6.1 blocks/CU)
//   gemm2:  x @ WoT^T + b_out -> out f32             (v5 champion)
//
// R15 scoreboard: every win was occupancy (R8 GEMM 3->6 blk/CU, R9/R13
// manifold waves, R15 VGPR cap); every schedule experiment regressed.
// manifold_v6 was the last 3-blocks/CU kernel -> v7 doubles its concurrency
// and halves the MFMA chain (split-K x4).
// ============================================================================

typedef __bf16 bf16_t;
typedef bf16_t bf16x8 __attribute__((ext_vector_type(8)));
typedef bf16_t bf16x4 __attribute__((ext_vector_type(4)));
typedef float  f32x4  __attribute__((ext_vector_type(4)));

#define IMG     448
#define PSZ     16
#define NHP     28
#define NPATCH  784
#define PDIM    768
#define DMODEL  512
#define MROWS   25088

__device__ __forceinline__ void gload16(void* lds, const void* g) {
  __builtin_amdgcn_global_load_lds(
      (__attribute__((address_space(1))) void*)(uintptr_t)g,
      (__attribute__((address_space(3))) void*)lds,
      16, 0, 0);
}

// ---------------------------------------------------------------------------
// prep_patchify: blk 0-95 WpT tiles; 96-159 WoT tiles; 160 Wcsg; 161+ patchify
// ---------------------------------------------------------------------------
__global__ __launch_bounds__(256) void prep_patchify(
    const float* __restrict__ Wp, const float* __restrict__ Wo,
    const float* __restrict__ Wc, const float* __restrict__ Ws,
    const float* __restrict__ images,
    bf16_t* __restrict__ WpT, bf16_t* __restrict__ WoT,
    bf16_t* __restrict__ Wcsg, bf16_t* __restrict__ Apat)
{
  __shared__ __align__(16) char shmem[64 * 65 * 4];
  const int tid = threadIdx.x;
  const int blk = blockIdx.x;

  if (blk == 160) {
    for (int idx = tid; idx < 8192; idx += 256) {
      const int r = idx >> 9, n = idx & 511;
      float v = 0.f;
      if (r < 8)       v = Wc[n * 8 + r];
      else if (r < 12) v = Ws[n * 4 + (r - 8)];
      Wcsg[idx] = (bf16_t)v;
    }
    return;
  }

  if (blk < 160) {
    float (*t)[65] = (float(*)[65])shmem;
    const float* src;  bf16_t* dst;  int K, N, bx, by;
    if (blk < 96) { src = Wp; dst = WpT; K = PDIM;   N = DMODEL;
                    bx = (blk & 7) * 64;        by = (blk >> 3) * 64; }
    else          { src = Wo; dst = WoT; K = DMODEL; N = DMODEL;
                    bx = ((blk - 96) & 7) * 64; by = ((blk - 96) >> 3) * 64; }
    const int tx = tid & 63, ty = tid >> 6;
    #pragma unroll
    for (int r = ty; r < 64; r += 4)
      t[r][tx] = src[(size_t)(by + r) * N + (bx + tx)];
    __syncthreads();
    #pragma unroll
    for (int r = ty; r < 64; r += 4)
      dst[(size_t)(bx + r) * K + (by + tx)] = (bf16_t)t[tx][r];
    return;
  }

  // ---- patchify ----
  bf16_t (*t)[456] = (bf16_t(*)[456])shmem;
  const int bid = blk - 161;
  const int b = bid / 84, rem = bid % 84;
  const int c = rem / 28, ph = rem % 28;
  const float* src = images + ((size_t)(b * 3 + c) * IMG + ph * PSZ) * IMG;

  #pragma unroll
  for (int idx = tid; idx < 16 * 112; idx += 256) {
    const int i = idx / 112, x4 = idx % 112;
    const float4 v = *(const float4*)(src + (size_t)i * IMG + x4 * 4);
    bf16x4 w;
    w[0] = (bf16_t)v.x; w[1] = (bf16_t)v.y; w[2] = (bf16_t)v.z; w[3] = (bf16_t)v.w;
    *(bf16x4*)&t[i][x4 * 4] = w;
  }
  __syncthreads();

  const size_t mbase = (size_t)b * NPATCH + (size_t)ph * NHP;
  #pragma unroll
  for (int idx = tid; idx < 28 * 64; idx += 256) {
    const int pw = idx >> 6, e = idx & 63;
    const int i = e >> 2, j4 = e & 3;
    const bf16x4 w = *(const bf16x4*)&t[i][pw * 16 + j4 * 4];
    *(bf16x4*)&Apat[(mbase + pw) * PDIM + c * 256 + i * 16 + j4 * 4] = w;
  }
}

// ---------------------------------------------------------------------------
// gemm v5 (champion): C[M][512] = A[M][KDIM] @ BT[512][KDIM]^T
// BM=64, BN=128, BK=64, 4 waves, 24 KB LDS, grid 1568, XCD swizzle,
// chunk-XOR swizzle c ^ (row&7) both sides; __launch_bounds__(256,6).
// Iteration-0 leading barrier peeled.
// ---------------------------------------------------------------------------
template<int KDIM, int EPI>
__global__ __launch_bounds__(256, 6) void gemm_bf16(
    const bf16_t* __restrict__ A, const bf16_t* __restrict__ BT,
    const float* __restrict__ bias, const float* __restrict__ pos,
    void* __restrict__ outp)
{
  __shared__ bf16_t As[64 * 64];    //  8 KB
  __shared__ bf16_t Bs[128 * 64];   // 16 KB
  constexpr int NT = KDIM / 64;

  const int tid  = threadIdx.x;
  const int orig = blockIdx.x;
  const int wg   = (orig & 7) * 196 + (orig >> 3);   // bijective, 1568=8*196
  const int n0   = (wg & 3) * 128;
  const int m0   = (wg >> 2) * 64;

  const int wave = tid >> 6, lane = tid & 63;

  const int ra = lane >> 3;
  const int ca = (lane & 7) ^ ra;
  const bf16_t* ag = A  + (size_t)(m0 + wave * 8 + ra) * KDIM + ca * 8;
  const bf16_t* bg = BT + (size_t)(n0 + wave * 8 + ra) * KDIM + ca * 8;
  bf16_t* al0 = As + (wave * 8) * 64;
  bf16_t* al1 = As + (wave * 8 + 32) * 64;
  bf16_t* bl0 = Bs + (wave * 8) * 64;
  bf16_t* bl1 = Bs + (wave * 8 + 32) * 64;
  bf16_t* bl2 = Bs + (wave * 8 + 64) * 64;
  bf16_t* bl3 = Bs + (wave * 8 + 96) * 64;

  const int wm = (wave >> 1) * 32;
  const int wn = (wave & 1) * 64;
  const int lr = lane & 15;
  const int lt = lane >> 4;

  f32x4 acc[2][4] = {};

  auto STAGE = [&](int k0) {
    gload16(al0, ag + k0);
    gload16(al1, ag + 32 * KDIM + k0);
    gload16(bl0, bg + k0);
    gload16(bl1, bg + 32 * KDIM + k0);
    gload16(bl2, bg + 64 * KDIM + k0);
    gload16(bl3, bg + 96 * KDIM + k0);
  };

  STAGE(0);                          // no barrier needed before first stage
  for (int t = 0; t < NT; ++t) {
    __syncthreads();                 // drains DMA (implies vmcnt 0)

    #pragma unroll
    for (int ks = 0; ks < 2; ++ks) {
      const int c = ks * 4 + lt;
      bf16x8 af[2], bfr[4];
      #pragma unroll
      for (int i = 0; i < 2; ++i) {
        const int row = wm + i * 16 + lr;
        af[i] = *(const bf16x8*)&As[row * 64 + ((c ^ (row & 7)) * 8)];
      }
      #pragma unroll
      for (int j = 0; j < 4; ++j) {
        const int row = wn + j * 16 + lr;
        bfr[j] = *(const bf16x8*)&Bs[row * 64 + ((c ^ (row & 7)) * 8)];
      }
      #pragma unroll
      for (int i = 0; i < 2; ++i)
        #pragma unroll
        for (int j = 0; j < 4; ++j)
          acc[i][j] = __builtin_amdgcn_mfma_f32_16x16x32_bf16(af[i], bfr[j], acc[i][j], 0, 0, 0);
    }

    if (t + 1 < NT) {
      __syncthreads();               // all waves' LDS reads done (WAR)
      STAGE((t + 1) * 64);
    }
  }

  const int q4 = lt << 2;
  const int colb = n0 + wn;
  #pragma unroll
  for (int i = 0; i < 2; ++i) {
    #pragma unroll
    for (int r = 0; r < 4; ++r) {
      const int mm = m0 + wm + i * 16 + q4 + r;
      if (EPI == 0) {
        const int pp = mm % NPATCH;
        const float* pe = pos + (size_t)pp * DMODEL;
        bf16_t* orow = (bf16_t*)outp + (size_t)mm * DMODEL;
        #pragma unroll
        for (int j = 0; j < 4; ++j) {
          const int nn = colb + j * 16 + lr;
          orow[nn] = (bf16_t)(acc[i][j][r] + bias[nn] + pe[nn]);
        }
      } else {
        float* orow = (float*)outp + (size_t)mm * DMODEL;
        #pragma unroll
        for (int j = 0; j < 4; ++j) {
          const int nn = colb + j * 16 + lr;
          orow[nn] = acc[i][j][r] + bias[nn];
        }
      }
    }
  }
}

// ---------------------------------------------------------------------------
// manifold_v7: split-K x4, 16 rows/block, grid = MROWS/16 = 1568.
// Phase A: wave kh (=w) computes coords/spinor partial for all 16 rows over
//   k in [kh*128, +128) — 4 MFMAs. Partials -> pbuf[kh][row][comp].
// Phase B: wave w owns rows w*4..w*4+3; lane owns cols lane*8..+8;
//   sum 4 partials + bias, K0, embed (reg-staged f32 We), residual, LN.
// ---------------------------------------------------------------------------
__global__ __launch_bounds__(256) void manifold_v7(
    bf16_t* __restrict__ x, const bf16_t* __restrict__ Wcsg,
    const float* __restrict__ b_coord, const float* __restrict__ b_spinor,
    const float* __restrict__ We, const float* __restrict__ be,
    const float* __restrict__ gamma, const float* __restrict__ beta)
{
  __shared__ float pbuf[4][16][12];   // [kquarter][row][comp], 3 KB

  const int tid  = threadIdx.x;
  const int w    = tid >> 6;          // wave = k-quarter in phase A
  const int lane = tid & 63;
  const int lr   = lane & 15;
  const int lk   = (lane >> 4) << 3;
  const int q4   = (lane >> 4) << 2;
  const size_t mbase = (size_t)blockIdx.x * 16;

  // ---- phase A: split-K x4 coords/spinor partials (raw) ----
  const bf16_t* xrow = x + (mbase + lr) * DMODEL + w * 128 + lk;
  const bf16_t* wrow = Wcsg + lr * DMODEL + w * 128 + lk;
  f32x4 acc1 = {0.f, 0.f, 0.f, 0.f};
  #pragma unroll
  for (int ks = 0; ks < 4; ++ks) {
    const bf16x8 bf = *(const bf16x8*)(xrow + ks * 32);
    const bf16x8 wf = *(const bf16x8*)(wrow + ks * 32);
    acc1 = __builtin_amdgcn_mfma_f32_16x16x32_bf16(wf, bf, acc1, 0, 0, 0);
  }
  if (q4 < 12) {
    #pragma unroll
    for (int r = 0; r < 4; ++r) pbuf[w][lr][q4 + r] = acc1[r];
  }
  __syncthreads();

  // ---- phase B: embed + residual + LN (4 rows per wave) ----
  const int n0 = lane * 8;
  f32x4 wlo[8], whi[8];
  #pragma unroll
  for (int dc = 0; dc < 8; ++dc) {
    wlo[dc] = *(const f32x4*)&We[dc * DMODEL + n0];
    whi[dc] = *(const f32x4*)&We[dc * DMODEL + n0 + 4];
  }
  const f32x4 beL = *(const f32x4*)&be[n0];
  const f32x4 beH = *(const f32x4*)&be[n0 + 4];
  const f32x4 gL  = *(const f32x4*)&gamma[n0];
  const f32x4 gH  = *(const f32x4*)&gamma[n0 + 4];
  const f32x4 btL = *(const f32x4*)&beta[n0];
  const f32x4 btH = *(const f32x4*)&beta[n0 + 4];
  float bc[8], bs[4];
  #pragma unroll
  for (int dc = 0; dc < 8; ++dc) bc[dc] = b_coord[dc];
  #pragma unroll
  for (int ds = 0; ds < 4; ++ds) bs[ds] = b_spinor[ds];

  #pragma unroll
  for (int rr = 0; rr < 4; ++rr) {
    const int rloc = w * 4 + rr;
    const float* p0 = &pbuf[0][rloc][0];
    const float* p1 = &pbuf[1][rloc][0];
    const float* p2 = &pbuf[2][rloc][0];
    const float* p3 = &pbuf[3][rloc][0];
    float c[8];
    #pragma unroll
    for (int dc = 0; dc < 8; ++dc)
      c[dc] = ((p0[dc] + p1[dc]) + (p2[dc] + p3[dc])) + bc[dc];
    float k0 = 0.f;
    #pragma unroll
    for (int ds = 0; ds < 4; ++ds) {
      const float s = ((p0[8 + ds] + p1[8 + ds]) + (p2[8 + ds] + p3[8 + ds])) + bs[ds];
      k0 += s * s;
    }

    const size_t row = mbase + rloc;
    const bf16x8 xv = *(const bf16x8*)(x + row * DMODEL + n0);

    float v[8];
    float s1 = 0.f, s2 = 0.f;
    #pragma unroll
    for (int e = 0; e < 4; ++e) {
      float xm = beL[e];
      #pragma unroll
      for (int dc = 0; dc < 8; ++dc) xm += c[dc] * wlo[dc][e];
      const float vv = xm * k0 + (float)xv[e];
      v[e] = vv; s1 += vv; s2 += vv * vv;
    }
    #pragma unroll
    for (int e = 0; e < 4; ++e) {
      float xm = beH[e];
      #pragma unroll
      for (int dc = 0; dc < 8; ++dc) xm += c[dc] * whi[dc][e];
      const float vv = xm * k0 + (float)xv[4 + e];
      v[4 + e] = vv; s1 += vv; s2 += vv * vv;
    }

    #pragma unroll
    for (int off = 1; off <= 32; off <<= 1) {
      s1 += __shfl_xor(s1, off, 64);
      s2 += __shfl_xor(s2, off, 64);
    }
    const float mu  = s1 * (1.f / 512.f);
    const float var = s2 * (1.f / 512.f) - mu * mu;
    const float rs  = rsqrtf(var + 1e-5f);

    bf16x8 o;
    #pragma unroll
    for (int e = 0; e < 4; ++e) {
      o[e]     = (bf16_t)((v[e]     - mu) * rs * gL[e] + btL[e]);
      o[4 + e] = (bf16_t)((v[4 + e] - mu) * rs * gH[e] + btH[e]);
    }
    *(bf16x8*)(x + row * DMODEL + n0) = o;
  }
}

// ---------------------------------------------------------------------------
extern "C" void kernel_launch(void* const* d_in, const int* in_sizes, int n_in,
                              void* d_out, int out_size, void* d_ws, size_t ws_size,
                              hipStream_t stream)
{
  const float* images    = (const float*)d_in[0];
  const float* W_patch   = (const float*)d_in[1];
  const float* b_patch   = (const float*)d_in[2];
  const float* pos_embed = (const float*)d_in[3];
  const float* W_coord   = (const float*)d_in[4];
  const float* b_coord   = (const float*)d_in[5];
  const float* W_spinor  = (const float*)d_in[6];
  const float* b_spinor  = (const float*)d_in[7];
  const float* W_embed   = (const float*)d_in[8];
  const float* b_embed   = (const float*)d_in[9];
  const float* ln_gamma  = (const float*)d_in[10];
  const float* ln_beta   = (const float*)d_in[11];
  const float* W_out     = (const float*)d_in[12];
  const float* b_out     = (const float*)d_in[13];
  float* out = (float*)d_out;

  const size_t SZ_APAT = (size_t)MROWS * PDIM * 2;     // 38,535,168
  const size_t SZ_X    = (size_t)MROWS * DMODEL * 2;   // 25,690,112
  const size_t SZ_WPT  = (size_t)DMODEL * PDIM * 2;    //    786,432
  const size_t SZ_WOT  = (size_t)DMODEL * DMODEL * 2;  //    524,288

  char* ws = (char*)d_ws;
  char* p  = ws;
  bf16_t* Apat = (bf16_t*)p;   p += SZ_APAT;
  bf16_t* x    = (bf16_t*)p;   p += SZ_X;
  bf16_t* WpT  = (bf16_t*)p;   p += SZ_WPT;
  bf16_t* WoT  = (bf16_t*)p;   p += SZ_WOT;
  bf16_t* Wcsg = (bf16_t*)p;

  hipLaunchKernelGGL(prep_patchify, dim3(161 + 32 * 3 * 28), dim3(256), 0, stream,
                     W_patch, W_out, W_coord, W_spinor, images,
                     WpT, WoT, Wcsg, Apat);

  hipLaunchKernelGGL((gemm_bf16<PDIM, 0>), dim3(1568), dim3(256), 0, stream,
                     Apat, WpT, b_patch, pos_embed, (void*)x);

  hipLaunchKernelGGL(manifold_v7, dim3(MROWS / 16), dim3(256), 0, stream,
                     x, Wcsg, b_coord, b_spinor, W_embed, b_embed, ln_gamma, ln_beta);

  hipLaunchKernelGGL((gemm_bf16<DMODEL, 1>), dim3(1568), dim3(256), 0, stream,
                     x, WoT, b_out, (const float*)nullptr, (void*)out);
}